// Round 9
// baseline (149.144 us; speedup 1.0000x reference)
//
#include <hip/hip_runtime.h>
#include <hip/hip_bf16.h>
#include <stdint.h>

#define BN_EPS 1e-3f

typedef __bf16 bf16x8 __attribute__((ext_vector_type(8)));
typedef float  f32x16 __attribute__((ext_vector_type(16)));

#define MFMA __builtin_amdgcn_mfma_f32_32x32x16_bf16

// Dims: B=256, F=64, Df=H=D=256, E=8. tile = 64 tokens (1 batch row).
// Grid 512 = 256 tiles x 2 expert-halves; eh = bid>>8 so the pair (t, t+256) lands on
// the SAME CU (512 WGs / 256 CUs round-robin) -> shared x L2 lines + local atomics.
// 512 thr = 8 waves; wave w = one nb (32 output cols), both 32-token halves.
// LDS: xb 32K + hb 32K + wrts 2K = 66K -> 2 WGs/CU = 16 waves/CU = 4 waves/SIMD.
// Register budget (512,4) = 128/wave: acc 32 + outacc 32 + B-ring 16 + A 16 + temps.
// ALL accumulators/fragments are NAMED variables (no arrays -> no scratch demotion).
// Depth-4 B prefetch ring chained across lgkm-only barriers (loads stay in flight).
static constexpr size_t WS_FOLD_OFF = 24ull * 131072ull;
static constexpr size_t WS_WRT_OFF  = WS_FOLD_OFF + 32768ull;
static constexpr size_t WS_WB_OFF   = WS_WRT_OFF + 2048ull;

// Swizzled LDS addr: frag-row fr (0..31 = k/8), token tok (0..63), 16B units.
#define XADDR64(fr, tok) (((fr) << 10) + ((((tok) ^ ((fr) & 31))) << 4))

// LDS-publish barrier: drain ds ops, NOT vmcnt (keep B loads in flight).
#define LBAR() do { \
  asm volatile("s_waitcnt lgkmcnt(0)" ::: "memory"); \
  __builtin_amdgcn_s_barrier(); \
  asm volatile("" ::: "memory"); \
} while (0)

// ---------------- Weight pack (+ BN fold in blocks 0-7) ----------------
__global__ __launch_bounds__(256) void pack_kernel(
    const float* __restrict__ W1, const float* __restrict__ W2, const float* __restrict__ Wo,
    const float* __restrict__ b1, const float* __restrict__ g1, const float* __restrict__ be1,
    const float* __restrict__ m1, const float* __restrict__ v1,
    const float* __restrict__ b2, const float* __restrict__ g2, const float* __restrict__ be2,
    const float* __restrict__ m2, const float* __restrict__ v2,
    __bf16* __restrict__ pk, float* __restrict__ fold) {
  __shared__ float sl[16 * 256];
  int bid = blockIdx.x;             // 384 = 24 mats * 16 ks
  int t = threadIdx.x;
  if (bid < 8) {                    // merged BN fold
    int i = bid * 256 + t;
    float s1 = g1[i] * rsqrtf(v1[i] + BN_EPS);
    fold[i]        = s1;
    fold[2048 + i] = (b1[i] - m1[i]) * s1 + be1[i];
    float s2 = g2[i] * rsqrtf(v2[i] + BN_EPS);
    fold[4096 + i] = s2;
    fold[6144 + i] = (b2[i] - m2[i]) * s2 + be2[i];
  }
  int m = bid >> 4, ks = bid & 15;
  int L = m >> 3, e = m & 7;
  const float* Ws = (L == 0 ? W1 : (L == 1 ? W2 : Wo)) + (size_t)e * 65536 + (size_t)ks * 16 * 256;
#pragma unroll
  for (int it = 0; it < 4; ++it) {
    int el4 = it * 256 + t;
    float4 v = *reinterpret_cast<const float4*>(Ws + (size_t)el4 * 4);
    *reinterpret_cast<float4*>(&sl[el4 * 4]) = v;
  }
  __syncthreads();
#pragma unroll
  for (int it = 0; it < 2; ++it) {
    int task = it * 256 + t;        // nb(8) x lane(64)
    int nb = task >> 6, l = task & 63;
    int colb = nb * 32 + (l & 31);
    int krow = (l >> 5) * 8;
    union { __bf16 h[8]; int4 v; } u;
#pragma unroll
    for (int i = 0; i < 8; ++i) u.h[i] = (__bf16)sl[(krow + i) * 256 + colb];
    size_t off = ((size_t)(m * 8 + nb) * 16 + ks) * 512 + (size_t)l * 8;
    *reinterpret_cast<int4*>(pk + off) = u.v;
  }
}

// ---------------- Routing pass 1: zero `out` + batch-partial sums ----------------
__global__ __launch_bounds__(256) void route1_kernel(
    const float* __restrict__ x, float* __restrict__ part, float* __restrict__ out) {
  int g = blockIdx.x;               // 512 WGs = 64 f x 8 bq
  int f = g & 63, bq = g >> 6;
  int t = threadIdx.x;
  float4 z = {0.f, 0.f, 0.f, 0.f};
  float4* oz = reinterpret_cast<float4*>(out + (size_t)g * 8192);  // 512*8192 = out_size
#pragma unroll
  for (int i = 0; i < 8; ++i) oz[i * 256 + t] = z;
  const float* xp = x + (size_t)(bq * 32) * 16384 + f * 256 + t;
  float s = 0.f;
#pragma unroll 4
  for (int bi = 0; bi < 32; ++bi) s += xp[(size_t)bi * 16384];
  part[(size_t)(bq * 64 + f) * 256 + t] = s;
}

// ---------------- Routing pass 2: reduce + softmax + wb ----------------
__global__ __launch_bounds__(256) void route2_kernel(
    const float* __restrict__ part, const float* __restrict__ Wr, const float* __restrict__ br,
    const float* __restrict__ bo, float* __restrict__ wrt, float* __restrict__ wb) {
  __shared__ float feat[256];
  __shared__ float lg[8];
  __shared__ float wsm[8];
  int f = blockIdx.x, t = threadIdx.x;
  float a = 0.f;
#pragma unroll
  for (int bq = 0; bq < 8; ++bq) a += part[(size_t)(bq * 64 + f) * 256 + t];
  feat[t] = a * (1.0f / 256.0f);
  __syncthreads();
  if (t < 8) {
    float s = br[t];
    for (int d = 0; d < 256; ++d) s += feat[d] * Wr[d * 8 + t];
    lg[t] = s;
  }
  __syncthreads();
  if (t == 0) {
    float mx = lg[0];
#pragma unroll
    for (int e = 1; e < 8; ++e) mx = fmaxf(mx, lg[e]);
    float ex[8]; float sum = 0.f;
#pragma unroll
    for (int e = 0; e < 8; ++e) { ex[e] = expf(lg[e] - mx); sum += ex[e]; }
    float inv = 1.0f / sum;
#pragma unroll
    for (int e = 0; e < 8; ++e) { float v = ex[e] * inv; wsm[e] = v; wrt[f * 8 + e] = v; }
  }
  __syncthreads();
  float o = 0.f;
#pragma unroll
  for (int e = 0; e < 8; ++e) o += wsm[e] * bo[e * 256 + t];
  wb[f * 256 + t] = o;
}

// ---------------- Main fused MoE ----------------
// Sweep: 16 ks steps, 2 MFMAs each. Depth-4 B ring (c0..c3) reloaded in-loop;
// at ks>=12 the reload pulls from pbn -> ring crosses the following barrier full.
// SWAP=1: acc = mfma(W, act) -> C rows = h-cols(32), cols = tokens.
template<int SWAP, int ZERO>
__device__ __forceinline__ void sweep64(
    const char* __restrict__ src, const __bf16* __restrict__ pb,
    const __bf16* __restrict__ pbn, int l, int l31, int hi,
    bf16x8& c0, bf16x8& c1, bf16x8& c2, bf16x8& c3,
    f32x16& accA, f32x16& accB) {
  if (ZERO) {
#pragma unroll
    for (int r = 0; r < 16; ++r) { accA[r] = 0.f; accB[r] = 0.f; }
  }
  bf16x8 a0 = *reinterpret_cast<const bf16x8*>(src + XADDR64(hi, l31));
  bf16x8 a1 = *reinterpret_cast<const bf16x8*>(src + XADDR64(hi, 32 + l31));

#define SW_STEP(KS, CV)                                                              \
  {                                                                                  \
    bf16x8 na0, na1;                                                                 \
    if ((KS) < 15) {                                                                 \
      na0 = *reinterpret_cast<const bf16x8*>(src + XADDR64(2 * ((KS) + 1) + hi, l31));        \
      na1 = *reinterpret_cast<const bf16x8*>(src + XADDR64(2 * ((KS) + 1) + hi, 32 + l31));   \
    }                                                                                \
    __builtin_amdgcn_s_setprio(1);                                                   \
    if (SWAP) { accA = MFMA(CV, a0, accA, 0, 0, 0); accB = MFMA(CV, a1, accB, 0, 0, 0); } \
    else      { accA = MFMA(a0, CV, accA, 0, 0, 0); accB = MFMA(a1, CV, accB, 0, 0, 0); } \
    __builtin_amdgcn_s_setprio(0);                                                   \
    CV = *reinterpret_cast<const bf16x8*>(                                           \
        (((KS) < 12) ? (pb + ((KS) + 4) * 512) : (pbn + ((KS) - 12) * 512)) + (size_t)l * 8); \
    if ((KS) < 15) { a0 = na0; a1 = na1; }                                           \
  }

  SW_STEP(0, c0)  SW_STEP(1, c1)  SW_STEP(2, c2)  SW_STEP(3, c3)
  SW_STEP(4, c0)  SW_STEP(5, c1)  SW_STEP(6, c2)  SW_STEP(7, c3)
  SW_STEP(8, c0)  SW_STEP(9, c1)  SW_STEP(10, c2) SW_STEP(11, c3)
  SW_STEP(12, c0) SW_STEP(13, c1) SW_STEP(14, c2) SW_STEP(15, c3)
#undef SW_STEP
}

// Epilogue for swapped phases: BN + relu (+ per-token wrt scale), pack bf16, LDS store.
__device__ __forceinline__ void epi64(
    const f32x16& accA, const f32x16& accB,
    const float* __restrict__ sA, const float* __restrict__ cA,
    char* __restrict__ dst, int l31, int hi, int wn, float w0, float w1) {
#pragma unroll
  for (int g = 0; g < 4; ++g) {
    float4 s4 = *reinterpret_cast<const float4*>(sA + 8 * g);
    float4 c4 = *reinterpret_cast<const float4*>(cA + 8 * g);
    int fr = wn * 4 + g;
    union { __bf16 h[4]; uint2 u; } pA, pB;
#pragma unroll
    for (int j = 0; j < 4; ++j) {
      float sj = (&s4.x)[j], cj = (&c4.x)[j];
      pA.h[j] = (__bf16)(w0 * fmaxf(accA[4 * g + j] * sj + cj, 0.f));
      pB.h[j] = (__bf16)(w1 * fmaxf(accB[4 * g + j] * sj + cj, 0.f));
    }
    *reinterpret_cast<uint2*>(dst + XADDR64(fr, l31) + hi * 8) = pA.u;
    *reinterpret_cast<uint2*>(dst + XADDR64(fr, 32 + l31) + hi * 8) = pB.u;
  }
}

__global__ __launch_bounds__(512, 4) void moe_kernel(
    const float* __restrict__ x, const __bf16* __restrict__ pk,
    const float* __restrict__ fold, const float* __restrict__ wrt,
    const float* __restrict__ wb, float* __restrict__ out) {
  __shared__ char xb[32768];
  __shared__ char hb[32768];
  __shared__ float wrts[512];
  const int tid = threadIdx.x;
  const int l = tid & 63;
  const int l31 = l & 31, hi = l >> 5;
  const int wn = __builtin_amdgcn_readfirstlane(tid >> 6);   // wave's nb, scalar
  const int bid = blockIdx.x;
  const int tile = bid & 255, eh = bid >> 8;   // (t, t+256) share a CU

#define PBO(L, e) (pk + (size_t)((((L) * 8 + (e)) * 8 + wn) * 8192))

  // ---- B prologue: ring c0..c3 <- PB(0, e_first) ks 0..3 (in flight during staging) ----
  const __bf16* pbf = PBO(0, eh * 4);
  bf16x8 rc0 = *reinterpret_cast<const bf16x8*>(pbf + 0 * 512 + (size_t)l * 8);
  bf16x8 rc1 = *reinterpret_cast<const bf16x8*>(pbf + 1 * 512 + (size_t)l * 8);
  bf16x8 rc2 = *reinterpret_cast<const bf16x8*>(pbf + 2 * 512 + (size_t)l * 8);
  bf16x8 rc3 = *reinterpret_cast<const bf16x8*>(pbf + 3 * 512 + (size_t)l * 8);

  // ---- stage x -> bf16 LDS (swizzled; coalesced global reads) ----
  {
    const float* xg = x + (size_t)tile * 16384;
#pragma unroll
    for (int i = 0; i < 4; ++i) {
      int u = i * 512 + tid;           // 2048 16B-units: tok(64) x k8(32)
      int tok = u >> 5, k8 = u & 31;
      const float* src = xg + (size_t)tok * 256 + k8 * 8;
      float4 v0 = *reinterpret_cast<const float4*>(src);
      float4 v1 = *reinterpret_cast<const float4*>(src + 4);
      union { __bf16 h[8]; int4 v; } p;
      p.h[0] = (__bf16)v0.x; p.h[1] = (__bf16)v0.y; p.h[2] = (__bf16)v0.z; p.h[3] = (__bf16)v0.w;
      p.h[4] = (__bf16)v1.x; p.h[5] = (__bf16)v1.y; p.h[6] = (__bf16)v1.z; p.h[7] = (__bf16)v1.w;
      *reinterpret_cast<int4*>(xb + XADDR64(k8, tok)) = p.v;
    }
  }
  wrts[tid] = wrt[tid];   // 512 = 64 f x 8 e

  f32x16 outA, outB;
#pragma unroll
  for (int r = 0; r < 16; ++r) { outA[r] = 0.f; outB[r] = 0.f; }

  LBAR();   // staging visible

  f32x16 accA, accB;
#pragma unroll 1
  for (int ep = 0; ep < 4; ++ep) {
    const int e = eh * 4 + ep;
    const __bf16* pb_l0 = PBO(0, e);
    const __bf16* pb_l1 = PBO(1, e);
    const __bf16* pb_l2 = PBO(2, e);
    const __bf16* pb_nx = (ep < 3) ? PBO(0, e + 1) : PBO(0, eh * 4);
    // L0: read xb -> acc (ring holds pb_l0 ks0..3 on entry)
    sweep64<1, 1>(xb, pb_l0, pb_l1, l, l31, hi, rc0, rc1, rc2, rc3, accA, accB);
    LBAR();   // prev L2 readers of hb are done
    epi64(accA, accB, fold + e * 256 + wn * 32 + 4 * hi,
          fold + 2048 + e * 256 + wn * 32 + 4 * hi, hb, l31, hi, wn, 1.f, 1.f);
    LBAR();   // h1 visible
    // L1: read hb -> acc (in-place; barriers separate read & write)
    sweep64<1, 1>(hb, pb_l1, pb_l2, l, l31, hi, rc0, rc1, rc2, rc3, accA, accB);
    LBAR();   // all reads done
    {
      float w0 = wrts[l31 * 8 + e];
      float w1 = wrts[(32 + l31) * 8 + e];
      epi64(accA, accB, fold + 4096 + e * 256 + wn * 32 + 4 * hi,
            fold + 6144 + e * 256 + wn * 32 + 4 * hi, hb, l31, hi, wn, w0, w1);
    }
    LBAR();   // h2 visible
    // L2: outacc += (wrt*h) @ Wo (direct MFMA accumulate; no barrier after)
    sweep64<0, 0>(hb, pb_l2, pb_nx, l, l31, hi, rc0, rc1, rc2, rc3, outA, outB);
  }
#undef PBO

  // ---- combine: 2 commutative fp32 atomics per element (deterministic) ----
  float* og = out + (size_t)tile * 16384;
  const int col = wn * 32 + l31;
#pragma unroll
  for (int r = 0; r < 16; ++r) {
    int fA = 4 * hi + (r & 3) + 8 * (r >> 2);        // token (= f) for accA rows
    float vA = outA[r];
    if (eh == 0) vA += wb[fA * 256 + col];
    unsafeAtomicAdd(og + fA * 256 + col, vA);
    int fB = 32 + fA;
    float vB = outB[r];
    if (eh == 0) vB += wb[fB * 256 + col];
    unsafeAtomicAdd(og + fB * 256 + col, vB);
  }
}

extern "C" void kernel_launch(void* const* d_in, const int* in_sizes, int n_in,
                              void* d_out, int out_size, void* d_ws, size_t ws_size,
                              hipStream_t stream) {
  const float* x   = (const float*)d_in[0];
  const float* Wr  = (const float*)d_in[1];
  const float* br  = (const float*)d_in[2];
  const float* W1  = (const float*)d_in[3];
  const float* b1  = (const float*)d_in[4];
  const float* g1  = (const float*)d_in[5];
  const float* be1 = (const float*)d_in[6];
  const float* m1  = (const float*)d_in[7];
  const float* v1  = (const float*)d_in[8];
  const float* W2  = (const float*)d_in[9];
  const float* b2  = (const float*)d_in[10];
  const float* g2  = (const float*)d_in[11];
  const float* be2 = (const float*)d_in[12];
  const float* m2  = (const float*)d_in[13];
  const float* v2  = (const float*)d_in[14];
  const float* Wo  = (const float*)d_in[15];
  const float* bo  = (const float*)d_in[16];
  float* out = (float*)d_out;

  __bf16* pk  = (__bf16*)d_ws;
  float* part = (float*)d_ws;                          // overlays pk; dead before pack
  float* fold = (float*)((char*)d_ws + WS_FOLD_OFF);
  float* wrt  = (float*)((char*)d_ws + WS_WRT_OFF);
  float* wb   = (float*)((char*)d_ws + WS_WB_OFF);

  hipLaunchKernelGGL(route1_kernel, dim3(512), dim3(256), 0, stream, x, part, out);
  hipLaunchKernelGGL(route2_kernel, dim3(64), dim3(256), 0, stream, part, Wr, br, bo, wrt, wb);
  hipLaunchKernelGGL(pack_kernel, dim3(384), dim3(256), 0, stream,
                     W1, W2, Wo, b1, g1, be1, m1, v1, b2, g2, be2, m2, v2, pk, fold);
  hipLaunchKernelGGL(moe_kernel, dim3(512), dim3(512), 0, stream, x, pk, fold, wrt, wb, out);
}

// Round 10
// 115.222 us; speedup vs baseline: 1.2944x; 1.2944x over previous
//
#include <hip/hip_runtime.h>
#include <hip/hip_bf16.h>
#include <stdint.h>

#define BN_EPS 1e-3f

typedef __bf16 bf16x8 __attribute__((ext_vector_type(8)));
typedef float  f32x16 __attribute__((ext_vector_type(16)));

#define MFMA __builtin_amdgcn_mfma_f32_32x32x16_bf16

// Dims: B=256, F=64, Df=H=D=256, E=8. tile = 64 tokens (1 batch row).
// Grid 512 = 256 tiles x 2 expert-halves; eh = bid>>8 -> pair (t, t+256) on the SAME CU.
// WG = 256 thr = 4 waves; wave wq owns nb pair {2wq, 2wq+1} (64 out cols) x 64 tok.
// TWO WGs/CU = 8 waves/CU = 2 waves/SIMD -> 256-reg budget per wave (NO spill), and
// two INDEPENDENT barrier domains: one WG computes while the other drains its barrier.
// LDS: xb 32K + hb 32K + wrts 2K = 66K -> 2 WGs/CU.
// Depth-2 B-ring chained across lgkm-only barriers; A depth-1 prefetch; setprio on MFMA.
static constexpr size_t WS_FOLD_OFF = 24ull * 131072ull;
static constexpr size_t WS_WRT_OFF  = WS_FOLD_OFF + 32768ull;
static constexpr size_t WS_WB_OFF   = WS_WRT_OFF + 2048ull;

// Swizzled LDS addr: frag-row fr (0..31 = k/8), token tok (0..63), 16B units.
#define XADDR64(fr, tok) (((fr) << 10) + ((((tok) ^ ((fr) & 31))) << 4))

// LDS-publish barrier: drain ds ops, NOT vmcnt (keep B loads in flight).
#define LBAR() do { \
  asm volatile("s_waitcnt lgkmcnt(0)" ::: "memory"); \
  __builtin_amdgcn_s_barrier(); \
  asm volatile("" ::: "memory"); \
} while (0)

// ---------------- Weight pack (+ BN fold in blocks 0-7) ----------------
__global__ __launch_bounds__(256) void pack_kernel(
    const float* __restrict__ W1, const float* __restrict__ W2, const float* __restrict__ Wo,
    const float* __restrict__ b1, const float* __restrict__ g1, const float* __restrict__ be1,
    const float* __restrict__ m1, const float* __restrict__ v1,
    const float* __restrict__ b2, const float* __restrict__ g2, const float* __restrict__ be2,
    const float* __restrict__ m2, const float* __restrict__ v2,
    __bf16* __restrict__ pk, float* __restrict__ fold) {
  __shared__ float sl[16 * 256];
  int bid = blockIdx.x;             // 384 = 24 mats * 16 ks
  int t = threadIdx.x;
  if (bid < 8) {                    // merged BN fold
    int i = bid * 256 + t;
    float s1 = g1[i] * rsqrtf(v1[i] + BN_EPS);
    fold[i]        = s1;
    fold[2048 + i] = (b1[i] - m1[i]) * s1 + be1[i];
    float s2 = g2[i] * rsqrtf(v2[i] + BN_EPS);
    fold[4096 + i] = s2;
    fold[6144 + i] = (b2[i] - m2[i]) * s2 + be2[i];
  }
  int m = bid >> 4, ks = bid & 15;
  int L = m >> 3, e = m & 7;
  const float* Ws = (L == 0 ? W1 : (L == 1 ? W2 : Wo)) + (size_t)e * 65536 + (size_t)ks * 16 * 256;
#pragma unroll
  for (int it = 0; it < 4; ++it) {
    int el4 = it * 256 + t;
    float4 v = *reinterpret_cast<const float4*>(Ws + (size_t)el4 * 4);
    *reinterpret_cast<float4*>(&sl[el4 * 4]) = v;
  }
  __syncthreads();
#pragma unroll
  for (int it = 0; it < 2; ++it) {
    int task = it * 256 + t;        // nb(8) x lane(64)
    int nb = task >> 6, l = task & 63;
    int colb = nb * 32 + (l & 31);
    int krow = (l >> 5) * 8;
    union { __bf16 h[8]; int4 v; } u;
#pragma unroll
    for (int i = 0; i < 8; ++i) u.h[i] = (__bf16)sl[(krow + i) * 256 + colb];
    size_t off = ((size_t)(m * 8 + nb) * 16 + ks) * 512 + (size_t)l * 8;
    *reinterpret_cast<int4*>(pk + off) = u.v;
  }
}

// ---------------- Routing pass 1: zero `out` + batch-partial sums ----------------
__global__ __launch_bounds__(256) void route1_kernel(
    const float* __restrict__ x, float* __restrict__ part, float* __restrict__ out) {
  int g = blockIdx.x;               // 512 WGs = 64 f x 8 bq
  int f = g & 63, bq = g >> 6;
  int t = threadIdx.x;
  float4 z = {0.f, 0.f, 0.f, 0.f};
  float4* oz = reinterpret_cast<float4*>(out + (size_t)g * 8192);  // 512*8192 = out_size
#pragma unroll
  for (int i = 0; i < 8; ++i) oz[i * 256 + t] = z;
  const float* xp = x + (size_t)(bq * 32) * 16384 + f * 256 + t;
  float s = 0.f;
#pragma unroll 4
  for (int bi = 0; bi < 32; ++bi) s += xp[(size_t)bi * 16384];
  part[(size_t)(bq * 64 + f) * 256 + t] = s;
}

// ---------------- Routing pass 2: reduce + softmax + wb ----------------
__global__ __launch_bounds__(256) void route2_kernel(
    const float* __restrict__ part, const float* __restrict__ Wr, const float* __restrict__ br,
    const float* __restrict__ bo, float* __restrict__ wrt, float* __restrict__ wb) {
  __shared__ float feat[256];
  __shared__ float lg[8];
  __shared__ float wsm[8];
  int f = blockIdx.x, t = threadIdx.x;
  float a = 0.f;
#pragma unroll
  for (int bq = 0; bq < 8; ++bq) a += part[(size_t)(bq * 64 + f) * 256 + t];
  feat[t] = a * (1.0f / 256.0f);
  __syncthreads();
  if (t < 8) {
    float s = br[t];
    for (int d = 0; d < 256; ++d) s += feat[d] * Wr[d * 8 + t];
    lg[t] = s;
  }
  __syncthreads();
  if (t == 0) {
    float mx = lg[0];
#pragma unroll
    for (int e = 1; e < 8; ++e) mx = fmaxf(mx, lg[e]);
    float ex[8]; float sum = 0.f;
#pragma unroll
    for (int e = 0; e < 8; ++e) { ex[e] = expf(lg[e] - mx); sum += ex[e]; }
    float inv = 1.0f / sum;
#pragma unroll
    for (int e = 0; e < 8; ++e) { float v = ex[e] * inv; wsm[e] = v; wrt[f * 8 + e] = v; }
  }
  __syncthreads();
  float o = 0.f;
#pragma unroll
  for (int e = 0; e < 8; ++e) o += wsm[e] * bo[e * 256 + t];
  wb[f * 256 + t] = o;
}

// ---------------- Main fused MoE ----------------
// Sweep: 16 ks steps x 4 MFMAs (2 nb x 2 token-halves). Depth-2 B-ring (c0*,c1*);
// reloads at distance 2; at ks=14/15 pulls next sweep's ks0/1 -> ring crosses barriers full.
// SWAP=1 (L0/L1): acc = mfma(W, act) -> C rows = h-cols, cols = tokens.
template<int SWAP, int ZERO>
__device__ __forceinline__ void sweep64(
    const char* __restrict__ src, const __bf16* __restrict__ pb,
    const __bf16* __restrict__ pbn, int l, int l31, int hi,
    bf16x8& c0x, bf16x8& c0y, bf16x8& c1x, bf16x8& c1y,
    f32x16& acc00, f32x16& acc01, f32x16& acc10, f32x16& acc11) {
  if (ZERO) {
#pragma unroll
    for (int r = 0; r < 16; ++r) { acc00[r] = 0.f; acc01[r] = 0.f; acc10[r] = 0.f; acc11[r] = 0.f; }
  }
  bf16x8 a0 = *reinterpret_cast<const bf16x8*>(src + XADDR64(hi, l31));
  bf16x8 a1 = *reinterpret_cast<const bf16x8*>(src + XADDR64(hi, 32 + l31));

#define SW_STEP(KS)                                                                       \
  {                                                                                       \
    bf16x8 na0, na1;                                                                      \
    if ((KS) < 15) {                                                                      \
      na0 = *reinterpret_cast<const bf16x8*>(src + XADDR64(2 * ((KS) + 1) + hi, l31));    \
      na1 = *reinterpret_cast<const bf16x8*>(src + XADDR64(2 * ((KS) + 1) + hi, 32 + l31)); \
    }                                                                                     \
    __builtin_amdgcn_s_setprio(1);                                                        \
    if (SWAP) {                                                                           \
      acc00 = MFMA(c0x, a0, acc00, 0, 0, 0); acc01 = MFMA(c0x, a1, acc01, 0, 0, 0);       \
      acc10 = MFMA(c0y, a0, acc10, 0, 0, 0); acc11 = MFMA(c0y, a1, acc11, 0, 0, 0);       \
    } else {                                                                              \
      acc00 = MFMA(a0, c0x, acc00, 0, 0, 0); acc01 = MFMA(a1, c0x, acc01, 0, 0, 0);       \
      acc10 = MFMA(a0, c0y, acc10, 0, 0, 0); acc11 = MFMA(a1, c0y, acc11, 0, 0, 0);       \
    }                                                                                     \
    __builtin_amdgcn_s_setprio(0);                                                        \
    c0x = c1x; c0y = c1y;                                                                 \
    {                                                                                     \
      const __bf16* pn = ((KS) < 14) ? (pb + ((KS) + 2) * 512) : (pbn + ((KS) - 14) * 512); \
      c1x = *reinterpret_cast<const bf16x8*>(pn + (size_t)l * 8);                         \
      c1y = *reinterpret_cast<const bf16x8*>(pn + 8192 + (size_t)l * 8);                  \
    }                                                                                     \
    if ((KS) < 15) { a0 = na0; a1 = na1; }                                                \
  }

  SW_STEP(0)  SW_STEP(1)  SW_STEP(2)  SW_STEP(3)
  SW_STEP(4)  SW_STEP(5)  SW_STEP(6)  SW_STEP(7)
  SW_STEP(8)  SW_STEP(9)  SW_STEP(10) SW_STEP(11)
  SW_STEP(12) SW_STEP(13) SW_STEP(14) SW_STEP(15)
#undef SW_STEP
}

// Epilogue for swapped phases: BN + relu (+ per-token wrt scale), pack bf16, LDS store.
__device__ __forceinline__ void epi64(
    const f32x16& acc00, const f32x16& acc01, const f32x16& acc10, const f32x16& acc11,
    const float* __restrict__ sA, const float* __restrict__ cA,
    char* __restrict__ dst, int l31, int hi, int wq, float w0, float w1) {
#pragma unroll
  for (int nbi = 0; nbi < 2; ++nbi) {
    const f32x16& aA = nbi ? acc10 : acc00;
    const f32x16& aB = nbi ? acc11 : acc01;
#pragma unroll
    for (int g = 0; g < 4; ++g) {
      float4 s4 = *reinterpret_cast<const float4*>(sA + nbi * 32 + 8 * g);
      float4 c4 = *reinterpret_cast<const float4*>(cA + nbi * 32 + 8 * g);
      int fr = (wq * 2 + nbi) * 4 + g;
      union { __bf16 h[4]; uint2 u; } pA, pB;
#pragma unroll
      for (int j = 0; j < 4; ++j) {
        float sj = (&s4.x)[j], cj = (&c4.x)[j];
        pA.h[j] = (__bf16)(w0 * fmaxf(aA[4 * g + j] * sj + cj, 0.f));
        pB.h[j] = (__bf16)(w1 * fmaxf(aB[4 * g + j] * sj + cj, 0.f));
      }
      *reinterpret_cast<uint2*>(dst + XADDR64(fr, l31) + hi * 8) = pA.u;
      *reinterpret_cast<uint2*>(dst + XADDR64(fr, 32 + l31) + hi * 8) = pB.u;
    }
  }
}

__global__ __launch_bounds__(256, 2) void moe_kernel(
    const float* __restrict__ x, const __bf16* __restrict__ pk,
    const float* __restrict__ fold, const float* __restrict__ wrt,
    const float* __restrict__ wb, float* __restrict__ out) {
  __shared__ char xb[32768];
  __shared__ char hb[32768];
  __shared__ float wrts[512];
  const int tid = threadIdx.x;
  const int l = tid & 63;
  const int l31 = l & 31, hi = l >> 5;
  const int wq = __builtin_amdgcn_readfirstlane(tid >> 6);   // wave's nb-pair, scalar
  const int bid = blockIdx.x;
  const int tile = bid & 255, eh = bid >> 8;   // (t, t+256) share a CU

#define PBO(L, e) (pk + (size_t)((((L) * 8 + (e)) * 8 + wq * 2) * 8192))

  // ---- B prologue: ring <- PB(0, e_first) ks0/ks1 for both nb (in flight during staging) ----
  const __bf16* pbf = PBO(0, eh * 4);
  bf16x8 c0x = *reinterpret_cast<const bf16x8*>(pbf + 0 * 512 + (size_t)l * 8);
  bf16x8 c0y = *reinterpret_cast<const bf16x8*>(pbf + 8192 + 0 * 512 + (size_t)l * 8);
  bf16x8 c1x = *reinterpret_cast<const bf16x8*>(pbf + 1 * 512 + (size_t)l * 8);
  bf16x8 c1y = *reinterpret_cast<const bf16x8*>(pbf + 8192 + 1 * 512 + (size_t)l * 8);

  // ---- stage x -> bf16 LDS (swizzled; coalesced global reads) ----
  {
    const float* xg = x + (size_t)tile * 16384;
#pragma unroll
    for (int i = 0; i < 8; ++i) {
      int u = i * 256 + tid;           // 2048 16B-units: tok(64) x k8(32)
      int tok = u >> 5, k8 = u & 31;
      const float* src = xg + (size_t)tok * 256 + k8 * 8;
      float4 v0 = *reinterpret_cast<const float4*>(src);
      float4 v1 = *reinterpret_cast<const float4*>(src + 4);
      union { __bf16 h[8]; int4 v; } p;
      p.h[0] = (__bf16)v0.x; p.h[1] = (__bf16)v0.y; p.h[2] = (__bf16)v0.z; p.h[3] = (__bf16)v0.w;
      p.h[4] = (__bf16)v1.x; p.h[5] = (__bf16)v1.y; p.h[6] = (__bf16)v1.z; p.h[7] = (__bf16)v1.w;
      *reinterpret_cast<int4*>(xb + XADDR64(k8, tok)) = p.v;
    }
  }
  wrts[tid] = wrt[tid];
  wrts[256 + tid] = wrt[256 + tid];

  f32x16 out00, out01, out10, out11;
#pragma unroll
  for (int r = 0; r < 16; ++r) { out00[r] = 0.f; out01[r] = 0.f; out10[r] = 0.f; out11[r] = 0.f; }

  LBAR();   // staging visible

  f32x16 acc00, acc01, acc10, acc11;
#pragma unroll 1
  for (int ep = 0; ep < 4; ++ep) {
    const int e = eh * 4 + ep;
    const __bf16* pb_l0 = PBO(0, e);
    const __bf16* pb_l1 = PBO(1, e);
    const __bf16* pb_l2 = PBO(2, e);
    const __bf16* pb_nx = (ep < 3) ? PBO(0, e + 1) : PBO(0, eh * 4);
    // L0: read xb -> acc (ring holds pb_l0 ks0/1 on entry)
    sweep64<1, 1>(xb, pb_l0, pb_l1, l, l31, hi, c0x, c0y, c1x, c1y, acc00, acc01, acc10, acc11);
    LBAR();   // prev L2 readers of hb are done
    epi64(acc00, acc01, acc10, acc11, fold + e * 256 + wq * 64 + 4 * hi,
          fold + 2048 + e * 256 + wq * 64 + 4 * hi, hb, l31, hi, wq, 1.f, 1.f);
    LBAR();   // h1 visible
    // L1: read hb -> acc (in-place; barriers separate read & write)
    sweep64<1, 1>(hb, pb_l1, pb_l2, l, l31, hi, c0x, c0y, c1x, c1y, acc00, acc01, acc10, acc11);
    LBAR();   // all reads done
    {
      float w0 = wrts[l31 * 8 + e];
      float w1 = wrts[(32 + l31) * 8 + e];
      epi64(acc00, acc01, acc10, acc11, fold + 4096 + e * 256 + wq * 64 + 4 * hi,
            fold + 6144 + e * 256 + wq * 64 + 4 * hi, hb, l31, hi, wq, w0, w1);
    }
    LBAR();   // h2 visible
    // L2: outacc += (wrt*h) @ Wo (direct MFMA accumulate; no barrier after)
    sweep64<0, 0>(hb, pb_l2, pb_nx, l, l31, hi, c0x, c0y, c1x, c1y, out00, out01, out10, out11);
  }
#undef PBO

  // ---- combine: 2 commutative fp32 atomics per element (deterministic) ----
  float* og = out + (size_t)tile * 16384;
#define OUTW(OV, NBI, HALF)                                              \
  {                                                                      \
    int col = (wq * 2 + (NBI)) * 32 + l31;                               \
    _Pragma("unroll")                                                    \
    for (int r = 0; r < 16; ++r) {                                       \
      int f = (HALF) * 32 + 4 * hi + (r & 3) + 8 * (r >> 2);             \
      float v = OV[r];                                                   \
      if (eh == 0) v += wb[f * 256 + col];                               \
      unsafeAtomicAdd(og + f * 256 + col, v);                            \
    }                                                                    \
  }
  OUTW(out00, 0, 0) OUTW(out01, 0, 1) OUTW(out10, 1, 0) OUTW(out11, 1, 1)
#undef OUTW
}

extern "C" void kernel_launch(void* const* d_in, const int* in_sizes, int n_in,
                              void* d_out, int out_size, void* d_ws, size_t ws_size,
                              hipStream_t stream) {
  const float* x   = (const float*)d_in[0];
  const float* Wr  = (const float*)d_in[1];
  const float* br  = (const float*)d_in[2];
  const float* W1  = (const float*)d_in[3];
  const float* b1  = (const float*)d_in[4];
  const float* g1  = (const float*)d_in[5];
  const float* be1 = (const float*)d_in[6];
  const float* m1  = (const float*)d_in[7];
  const float* v1  = (const float*)d_in[8];
  const float* W2  = (const float*)d_in[9];
  const float* b2  = (const float*)d_in[10];
  const float* g2  = (const float*)d_in[11];
  const float* be2 = (const float*)d_in[12];
  const float* m2  = (const float*)d_in[13];
  const float* v2  = (const float*)d_in[14];
  const float* Wo  = (const float*)d_in[15];
  const float* bo  = (const float*)d_in[16];
  float* out = (float*)d_out;

  __bf16* pk  = (__bf16*)d_ws;
  float* part = (float*)d_ws;                          // overlays pk; dead before pack
  float* fold = (float*)((char*)d_ws + WS_FOLD_OFF);
  float* wrt  = (float*)((char*)d_ws + WS_WRT_OFF);
  float* wb   = (float*)((char*)d_ws + WS_WB_OFF);

  hipLaunchKernelGGL(route1_kernel, dim3(512), dim3(256), 0, stream, x, part, out);
  hipLaunchKernelGGL(route2_kernel, dim3(64), dim3(256), 0, stream, part, Wr, br, bo, wrt, wb);
  hipLaunchKernelGGL(pack_kernel, dim3(384), dim3(256), 0, stream,
                     W1, W2, Wo, b1, g1, be1, m1, v1, b2, g2, be2, m2, v2, pk, fold);
  hipLaunchKernelGGL(moe_kernel, dim3(512), dim3(256), 0, stream, x, pk, fold, wrt, wb, out);
}